// Round 3
// baseline (524.341 us; speedup 1.0000x reference)
//
#include <hip/hip_runtime.h>

typedef float f32x4 __attribute__((ext_vector_type(4)));
typedef __bf16 bf16x8 __attribute__((ext_vector_type(8)));
typedef unsigned short u16x8 __attribute__((ext_vector_type(8)));

// B=65536, IN=1260 (19 full chunks of 64 + tail 44), H=40
// packed gate cols: [i(0..39), g(40..79), o(80..119)], padded to 128. f-gate dropped (c0=0).

__device__ __forceinline__ unsigned short f2bf(float f) {
  unsigned int u = __builtin_bit_cast(unsigned int, f);
  u = (u + 0x7FFFu + ((u >> 16) & 1u)) >> 16;   // RNE
  return (unsigned short)u;
}
__device__ __forceinline__ float sigm(float v) { return 1.0f / (1.0f + __expf(-v)); }
__device__ __forceinline__ float tanh_(float v) { return 1.0f - 2.0f / (__expf(2.0f * v) + 1.0f); }

__device__ __forceinline__ int srow_of(int col) {
  return col + (col < 40 ? 0 : (col < 80 ? 40 : 80));   // packed col -> original gate row
}

// ---------- prep: fragment-major bf16 weight images + fused biases ----------
// W0f layout: idx = c*8192 + ks*4096 + l4*1024 + col*8 + j  <=>  element (col, k=c*64+ks*32+l4*8+j)
// W1f/W2f:    idx = ks*4096 + l4*1024 + col*8 + j           <=>  element (col, k=ks*32+l4*8+j), k>=40 -> 0
__global__ __launch_bounds__(256) void prep_kernel(
    const float* __restrict__ W_ih0, const float* __restrict__ b_ih0, const float* __restrict__ b_hh0,
    const float* __restrict__ W_ih1, const float* __restrict__ b_ih1, const float* __restrict__ b_hh1,
    const float* __restrict__ W_ih2, const float* __restrict__ b_ih2, const float* __restrict__ b_hh2,
    unsigned short* __restrict__ W0f, unsigned short* __restrict__ W1f,
    unsigned short* __restrict__ W2f, float* __restrict__ bias)
{
  int idx = blockIdx.x * 256 + threadIdx.x;   // 0..163839
  {
    int j = idx & 7, col = (idx >> 3) & 127, l4 = (idx >> 10) & 3, ks = (idx >> 12) & 1, c = idx >> 13;
    int k = c * 64 + ks * 32 + l4 * 8 + j;
    unsigned short v = 0;
    if (col < 120 && k < 1260) v = f2bf(W_ih0[srow_of(col) * 1260 + k]);
    W0f[idx] = v;
  }
  if (idx < 8192) {
    int j = idx & 7, col = (idx >> 3) & 127, l4 = (idx >> 10) & 3, ks = idx >> 12;
    int k = ks * 32 + l4 * 8 + j;
    unsigned short v1 = 0, v2 = 0;
    if (col < 120 && k < 40) {
      int sr = srow_of(col);
      v1 = f2bf(W_ih1[sr * 40 + k]);
      v2 = f2bf(W_ih2[sr * 40 + k]);
    }
    W1f[idx] = v1;
    W2f[idx] = v2;
  }
  if (idx < 384) {
    int l = idx >> 7, col = idx & 127;
    float v = 0.0f;
    if (col < 120) {
      int sr = srow_of(col);
      v = (l == 0) ? (b_ih0[sr] + b_hh0[sr])
        : (l == 1) ? (b_ih1[sr] + b_hh1[sr])
                   : (b_ih2[sr] + b_hh2[sr]);
    }
    bias[idx] = v;
  }
}

// ---------- main: barrier-free, wave-private. 4 waves/block x 16 rows/wave ----------
__global__ __launch_bounds__(256, 4) void lstm_main(
    const float* __restrict__ x,
    const unsigned short* __restrict__ W0f,
    const unsigned short* __restrict__ W1f,
    const unsigned short* __restrict__ W2f,
    const float* __restrict__ bias,      // [3][128]
    const float* __restrict__ W_out,     // [4][40]
    const float* __restrict__ b_out,     // [4]
    float* __restrict__ out)
{
  __shared__ __align__(16) float gbuf[4][16 * 124];          // 31.0 KB: wave-private gates (f32)
  __shared__ __align__(16) unsigned short hbuf[4][16 * 64];  //  8.0 KB: wave-private h (bf16, swizzled)

  const int tid = threadIdx.x;
  const int wave = tid >> 6;
  const int lane = tid & 63;
  const int l15 = lane & 15;
  const int l4 = lane >> 4;
  const long R = (long)blockIdx.x * 64 + wave * 16;

  float* gw = gbuf[wave];
  unsigned short* hw = hbuf[wave];

  // zero hbuf tail (k=40..63) once; k<40 always overwritten by act_store
#pragma unroll
  for (int it = 0; it < 6; ++it) {
    int idx = it * 64 + lane;                 // 0..383
    int row = idx / 24;
    int kk = 40 + (idx - row * 24);
    int byte = row * 128 + ((kk * 2) ^ ((row & 7) << 4));
    *(unsigned short*)((char*)hw + byte) = 0;
  }

  f32x4 acc[8];
#pragma unroll
  for (int i = 0; i < 8; ++i) acc[i] = (f32x4){0.0f, 0.0f, 0.0f, 0.0f};

  auto cvt8 = [](f32x4 a0, f32x4 a1) -> bf16x8 {
    u16x8 u;
#pragma unroll
    for (int j = 0; j < 4; ++j) { u[j] = f2bf(a0[j]); u[4 + j] = f2bf(a1[j]); }
    return __builtin_bit_cast(bf16x8, u);
  };

  // ---- layer-0 GEMM: stream x from global, W fragments from L1/L2 ----
  const float* xp = x + (R + l15) * 1260 + l4 * 8;          // lane's row, k-base l4*8
  const unsigned short* wp = W0f + l4 * 1024 + l15 * 8;     // lane's fragment base

#pragma unroll 2
  for (int c = 0; c < 19; ++c) {
#pragma unroll
    for (int ks = 0; ks < 2; ++ks) {
      f32x4 a0 = *(const f32x4*)(xp + ks * 32);
      f32x4 a1 = *(const f32x4*)(xp + ks * 32 + 4);
      bf16x8 af = cvt8(a0, a1);
      const unsigned short* wq = wp + ks * 4096;
#pragma unroll
      for (int ct = 0; ct < 8; ++ct) {
        bf16x8 wf = *(const bf16x8*)(wq + ct * 128);
        acc[ct] = __builtin_amdgcn_mfma_f32_16x16x32_bf16(af, wf, acc[ct], 0, 0, 0);
      }
    }
    xp += 64;
    wp += 8192;
  }
  // tail chunk c=19 (k 1216..1279, valid < 1260): quad validity is all-or-nothing
  {
    const f32x4 z = {0.0f, 0.0f, 0.0f, 0.0f};
    {
      f32x4 a0 = *(const f32x4*)(xp);           // k 1216+l4*8 .. +3, always valid
      f32x4 a1 = *(const f32x4*)(xp + 4);
      bf16x8 af = cvt8(a0, a1);
#pragma unroll
      for (int ct = 0; ct < 8; ++ct)
        acc[ct] = __builtin_amdgcn_mfma_f32_16x16x32_bf16(af, *(const bf16x8*)(wp + ct * 128), acc[ct], 0, 0, 0);
    }
    {
      f32x4 a0 = (l4 < 2) ? *(const f32x4*)(xp + 32) : z;   // k 1248+l4*8
      f32x4 a1 = (l4 < 1) ? *(const f32x4*)(xp + 36) : z;
      bf16x8 af = cvt8(a0, a1);
#pragma unroll
      for (int ct = 0; ct < 8; ++ct)
        acc[ct] = __builtin_amdgcn_mfma_f32_16x16x32_bf16(af, *(const bf16x8*)(wp + 4096 + ct * 128), acc[ct], 0, 0, 0);
    }
  }

  // ---- epilogue (all wave-private; compiler orders LDS via lgkmcnt, no barriers) ----
  auto store_gates = [&](const float* bp) {
#pragma unroll
    for (int ct = 0; ct < 8; ++ct) {
      int col = ct * 16 + l15;
      if (col < 120) {
        float bv = bp[col];
#pragma unroll
        for (int r = 0; r < 4; ++r)
          gw[(l4 * 4 + r) * 124 + col] = acc[ct][r] + bv;
      }
    }
  };

  auto act_store = [&]() {   // gates(gw) -> h bf16 -> hw (swizzled)
#pragma unroll
    for (int it = 0; it < 10; ++it) {
      int idx = it * 64 + lane;               // 0..639
      int row = idx / 40;
      int h = idx - row * 40;
      const float* gr = gw + row * 124;
      float i = sigm(gr[h]);
      float g = tanh_(gr[40 + h]);
      float o = sigm(gr[80 + h]);
      float hv = o * tanh_(i * g);            // c = i*g (c_prev = 0)
      int byte = row * 128 + ((h * 2) ^ ((row & 7) << 4));
      *(unsigned short*)((char*)hw + byte) = f2bf(hv);
    }
  };

  auto small_gemm = [&](const unsigned short* Wf) {
#pragma unroll
    for (int ks = 0; ks < 2; ++ks) {
      int byte = l15 * 128 + (((ks * 32 + l4 * 8) * 2) ^ ((l15 & 7) << 4));
      bf16x8 af = *(const bf16x8*)((const char*)hw + byte);
      const unsigned short* wq = Wf + ks * 4096 + l4 * 1024 + l15 * 8;
#pragma unroll
      for (int ct = 0; ct < 8; ++ct) {
        bf16x8 wf = *(const bf16x8*)(wq + ct * 128);
        acc[ct] = __builtin_amdgcn_mfma_f32_16x16x32_bf16(af, wf, acc[ct], 0, 0, 0);
      }
    }
  };

  store_gates(bias);        // layer-0 gates
  act_store();              // h0 -> hw

#pragma unroll
  for (int i = 0; i < 8; ++i) acc[i] = (f32x4){0.0f, 0.0f, 0.0f, 0.0f};
  small_gemm(W1f);
  store_gates(bias + 128);  // layer-1 gates
  act_store();              // h1 -> hw

#pragma unroll
  for (int i = 0; i < 8; ++i) acc[i] = (f32x4){0.0f, 0.0f, 0.0f, 0.0f};
  small_gemm(W2f);
  store_gates(bias + 256);  // layer-2 gates

  // final activation: h2 (f32) in place at gw[row][0..39]
#pragma unroll
  for (int it = 0; it < 10; ++it) {
    int idx = it * 64 + lane;
    int row = idx / 40;
    int h = idx - row * 40;
    float* gr = gw + row * 124;
    float i = sigm(gr[h]);
    float g = tanh_(gr[40 + h]);
    float o = sigm(gr[80 + h]);
    gr[h] = o * tanh_(i * g);                 // writes col<40, reads col>=40 of others: no hazard
  }

  // output head: out[row][oi] = b_out[oi] + sum_h W_out[oi][h] * h2[row][h]
  {
    int row = lane >> 2, oi = lane & 3;
    const float* wo = W_out + oi * 40;
    float s = b_out[oi];
    const float* hr = gw + row * 124;
#pragma unroll
    for (int h = 0; h < 40; ++h) s = fmaf(wo[h], hr[h], s);
    out[(R + row) * 4 + oi] = s;
  }
}

extern "C" void kernel_launch(void* const* d_in, const int* in_sizes, int n_in,
                              void* d_out, int out_size, void* d_ws, size_t ws_size,
                              hipStream_t stream) {
  const float* x     = (const float*)d_in[0];
  const float* W_ih0 = (const float*)d_in[1];
  const float* b_ih0 = (const float*)d_in[3];
  const float* b_hh0 = (const float*)d_in[4];
  const float* W_ih1 = (const float*)d_in[5];
  const float* b_ih1 = (const float*)d_in[7];
  const float* b_hh1 = (const float*)d_in[8];
  const float* W_ih2 = (const float*)d_in[9];
  const float* b_ih2 = (const float*)d_in[11];
  const float* b_hh2 = (const float*)d_in[12];
  const float* W_out = (const float*)d_in[13];
  const float* b_out = (const float*)d_in[14];

  // workspace: W0f 163840 ush + W1f 8192 + W2f 8192 + bias 384 f32  (~362 KB)
  unsigned short* W0f = (unsigned short*)d_ws;
  unsigned short* W1f = W0f + 163840;
  unsigned short* W2f = W1f + 8192;
  float* bias = (float*)(W2f + 8192);

  if (ws_size < (size_t)(163840 + 8192 + 8192) * 2 + 384 * 4) return;

  prep_kernel<<<640, 256, 0, stream>>>(W_ih0, b_ih0, b_hh0,
                                       W_ih1, b_ih1, b_hh1,
                                       W_ih2, b_ih2, b_hh2,
                                       W0f, W1f, W2f, bias);
  lstm_main<<<1024, 256, 0, stream>>>(x, W0f, W1f, W2f, bias, W_out, b_out, (float*)d_out);
}